// Round 6
// baseline (273.750 us; speedup 1.0000x reference)
//
#include <hip/hip_runtime.h>

#define DI __device__ __forceinline__

typedef __attribute__((ext_vector_type(8))) short s16x8;
typedef __attribute__((ext_vector_type(4))) short s16x4;
typedef __attribute__((ext_vector_type(4))) float f32x4;

DI unsigned short f2bf(float f){
  unsigned u = __float_as_uint(f);
  u = (u + 0x7FFFu + ((u >> 16) & 1u)) >> 16;
  return (unsigned short)u;
}
DI float bf2f(unsigned short h){
  return __uint_as_float(((unsigned)h) << 16);
}

DI void gll16(const void* g, void* l){
  __builtin_amdgcn_global_load_lds((const __attribute__((address_space(1))) void*)g,
                                   (__attribute__((address_space(3))) void*)l, 16, 0, 0);
}

// ---------------- elementwise fp32 -> bf16 ----------------
__global__ void cvt_kernel(const float* __restrict__ in, unsigned short* __restrict__ out, int n8){
  int i = blockIdx.x * blockDim.x + threadIdx.x;
  if (i >= n8) return;
  const float4* p = (const float4*)in + (size_t)i * 2;
  float4 a = p[0], b = p[1];
  s16x8 o;
  o[0] = (short)f2bf(a.x); o[1] = (short)f2bf(a.y); o[2] = (short)f2bf(a.z); o[3] = (short)f2bf(a.w);
  o[4] = (short)f2bf(b.x); o[5] = (short)f2bf(b.y); o[6] = (short)f2bf(b.z); o[7] = (short)f2bf(b.w);
  ((s16x8*)out)[i] = o;
}

// ---------------- transpose + convert: in fp32 [R][C] -> out bf16 [C][R] ----------------
__global__ void transpose_cvt(const float* __restrict__ in, unsigned short* __restrict__ out, int R, int C){
  __shared__ float t[32][33];
  int c0 = blockIdx.x * 32, r0 = blockIdx.y * 32;
  int tx = threadIdx.x, ty = threadIdx.y; // 32 x 8
  #pragma unroll
  for (int i = 0; i < 4; i++)
    t[ty + i*8][tx] = in[(size_t)(r0 + ty + i*8) * C + c0 + tx];
  __syncthreads();
  #pragma unroll
  for (int i = 0; i < 4; i++)
    out[(size_t)(c0 + ty + i*8) * R + r0 + tx] = f2bf(t[tx][ty + i*8]);
}

// ---------------- GEMM (m97 structure): C[M x N] = A[M x K] * Wt[N x K]^T + bias ----------------
// MODE 0 (BM=128): qkv -> qbuf rows, ktile swz, vtile swz. MODE 1 (BM=64): proj -> fp32 out.
template<int MODE, int BM>
__launch_bounds__(256)
__global__ void gemm_kernel(const unsigned short* __restrict__ A,
                            const unsigned short* __restrict__ Wt,
                            const float* __restrict__ bias,
                            int N,
                            unsigned short* __restrict__ qb,
                            unsigned short* __restrict__ kb,
                            unsigned short* __restrict__ vt,
                            float* __restrict__ out)
{
  constexpr int MI = BM / 32;          // m-frags per wave
  constexpr int AC = BM / 32;          // A staging chunk-groups
  const int K = 1024;
  __shared__ unsigned short As[BM * 64];
  __shared__ unsigned short Bs[128 * 64];
  int m0 = blockIdx.y * BM, n0 = blockIdx.x * 128;
  int tid = threadIdx.x;
  int lane = tid & 63, w = tid >> 6;
  int row_l = lane & 15, kgrp = lane >> 4;
  int wm = (w >> 1) * (MI * 16), wn = (w & 1) * 64;

  const unsigned short* asrc[AC];
  const unsigned short* bsrc[4];
  int ldsoA[AC], ldsoB[4];
  int chunk = (lane & 7) ^ (lane >> 3);
  #pragma unroll
  for (int c4 = 0; c4 < AC; c4++){
    int r = c4*32 + w*8 + (lane >> 3);
    asrc[c4] = A + (size_t)(m0 + r) * K + chunk*8;
    ldsoA[c4] = (c4*32 + w*8) * 64;
  }
  #pragma unroll
  for (int c4 = 0; c4 < 4; c4++){
    int r = c4*32 + w*8 + (lane >> 3);
    bsrc[c4] = Wt + (size_t)(n0 + r) * K + chunk*8;
    ldsoB[c4] = (c4*32 + w*8) * 64;
  }
  int eA[MI], eB[4];
  #pragma unroll
  for (int i = 0; i < MI; i++){
    int ra = wm + i*16 + row_l;
    eA[i] = (ra*64 + kgrp*8) ^ ((ra & 7) << 3);
  }
  #pragma unroll
  for (int i = 0; i < 4; i++){
    int rb = wn + i*16 + row_l;
    eB[i] = (rb*64 + kgrp*8) ^ ((rb & 7) << 3);
  }

  f32x4 acc[MI][4];
  #pragma unroll
  for (int i = 0; i < MI; i++)
    #pragma unroll
    for (int j = 0; j < 4; j++)
      acc[i][j] = (f32x4){0.f, 0.f, 0.f, 0.f};

  for (int k0 = 0; k0 < K; k0 += 64){
    #pragma unroll
    for (int c4 = 0; c4 < AC; c4++)
      gll16(asrc[c4] + k0, (void*)(As + ldsoA[c4]));
    #pragma unroll
    for (int c4 = 0; c4 < 4; c4++)
      gll16(bsrc[c4] + k0, (void*)(Bs + ldsoB[c4]));
    __syncthreads();
    #pragma unroll
    for (int kc = 0; kc < 2; kc++){
      s16x8 af[MI], bfr[4];
      #pragma unroll
      for (int mi = 0; mi < MI; mi++)
        af[mi] = *(const s16x8*)&As[eA[mi] ^ (kc*32)];
      #pragma unroll
      for (int ni = 0; ni < 4; ni++)
        bfr[ni] = *(const s16x8*)&Bs[eB[ni] ^ (kc*32)];
      #pragma unroll
      for (int mi = 0; mi < MI; mi++)
        #pragma unroll
        for (int ni = 0; ni < 4; ni++)
          acc[mi][ni] = __builtin_amdgcn_mfma_f32_16x16x32_bf16(af[mi], bfr[ni], acc[mi][ni], 0, 0, 0);
    }
    __syncthreads();
  }

  #pragma unroll
  for (int mi = 0; mi < MI; mi++){
    #pragma unroll
    for (int ni = 0; ni < 4; ni++){
      #pragma unroll
      for (int j = 0; j < 4; j++){
        int gr = m0 + wm + mi*16 + kgrp*4 + j;
        int gc = n0 + wn + ni*16 + row_l;
        float v = acc[mi][ni][j] + bias[gc];
        if (MODE == 0){
          int h = gc / 192, cc = gc % 192;
          int b = gr >> 11, s = gr & 2047;
          unsigned short bv = f2bf(v);
          if (cc < 64){
            qb[(size_t)gr * 1024 + h*64 + cc] = bv;
          } else if (cc < 128){
            int d = cc - 64; int kt = s >> 6, kk = s & 63;
            kb[(size_t)((b*16 + h)*32 + kt) * 4096 + ((kk*64 + d) ^ ((kk & 7) << 3))] = bv;
          } else {
            int d = cc - 128; int kt = s >> 6, kk = s & 63;
            vt[(size_t)((b*16 + h)*32 + kt) * 4096 + ((d*64 + kk) ^ ((d & 7) << 3))] = bv;
          }
        } else {
          out[(size_t)gr * N + gc] = v;
        }
      }
    }
  }
}

// ---------------- V suffix sums (64-key granularity): sufv[bh][t in 0..32][64d] ----------------
__global__ void sufv_kernel(const unsigned short* __restrict__ vt, float* __restrict__ sufv){
  __shared__ float tot[4][64];
  int bh = blockIdx.x;                 // 32
  int tid = threadIdx.x;               // 256
  int tq = tid >> 6, d = tid & 63;
  const unsigned short* base = vt + (size_t)bh * 32 * 4096;
  float s[8];
  float run = 0.f;
  for (int j = 7; j >= 0; j--){
    int t = tq*8 + j;
    float rs = 0.f;
    #pragma unroll
    for (int c = 0; c < 8; c++){
      int idx = (d*64 + c*8) ^ ((d & 7) << 3);
      s16x8 v = *(const s16x8*)&base[(size_t)t*4096 + idx];
      #pragma unroll
      for (int e = 0; e < 8; e++) rs += bf2f((unsigned short)v[e]);
    }
    run += rs; s[j] = run;
  }
  tot[tq][d] = run;
  __syncthreads();
  float carry = 0.f;
  for (int t2 = tq+1; t2 < 4; t2++) carry += tot[t2][d];
  #pragma unroll
  for (int j = 0; j < 8; j++)
    sufv[((size_t)bh*33 + tq*8 + j)*64 + d] = s[j] + carry;
  if (tid < 64) sufv[((size_t)bh*33 + 32)*64 + tid] = 0.f;
}

// ---------------- D-pass: invDQ[b][q][k] = 1 / sum_h exp(s_h(q,k)) over causal triangle ----------------
// kt-major tile enumeration + XCD swizzle; 4-buffer 2-deep LDS ring (R3 form).
__launch_bounds__(256)
__global__ void dpass_kernel(const unsigned short* __restrict__ qbuf,
                             const unsigned short* __restrict__ kb,
                             float* __restrict__ invDQ)
{
  __shared__ unsigned short Kst[4][4096];
  int bid = blockIdx.x;                       // 1056 = 8 * 132
  int blk = (bid & 7) * 132 + (bid >> 3);     // XCD swizzle (bijective)
  int b = blk / 528, t = blk % 528;
  // kt-major: f(kt) = kt*(65-kt)/2; t in [f(kt), f(kt+1)) -> qt = kt + t - f(kt)
  int kt = (int)(32.5f - sqrtf(1056.25f - 2.f*t));
  while (kt*(65-kt)/2 > t) kt--;
  while ((kt+1)*(64-kt)/2 <= t) kt++;
  int qt = kt + (t - kt*(65-kt)/2);

  int tid = threadIdx.x, lane = tid & 63, w = tid >> 6;
  int row_l = lane & 15, kgrp = lane >> 4;

  const unsigned short* ktb = kb + ((size_t)(b*16)*32 + kt) * 4096;
  int sgoff = (w*128 + lane)*8;

  auto stage = [&](int hh, int buf){
    const unsigned short* src = ktb + (size_t)hh * 131072;
    gll16(src + sgoff,       (void*)(&Kst[buf][0] + w*1024));
    gll16(src + sgoff + 512, (void*)(&Kst[buf][0] + w*1024 + 512));
  };

  int e0[4];
  #pragma unroll
  for (int ks = 0; ks < 4; ks++){
    int row = ks*16 + row_l;
    e0[ks] = (row*64 + kgrp*8) ^ ((row & 7) << 3);
  }

  stage(0, 0);
  stage(1, 1);

  f32x4 esum[4];
  #pragma unroll
  for (int ks = 0; ks < 4; ks++) esum[ks] = (f32x4){0.f,0.f,0.f,0.f};

  const unsigned short* qrow_p = qbuf + (size_t)(b*2048 + qt*64 + w*16 + row_l) * 1024;
  s16x8 qf0 = *(const s16x8*)&qrow_p[kgrp*8];
  s16x8 qf1 = *(const s16x8*)&qrow_p[32 + kgrp*8];

  for (int h = 0; h < 16; h++){
    s16x8 qn0, qn1;
    if (h < 15){
      qn0 = *(const s16x8*)&qrow_p[(h+1)*64 + kgrp*8];
      qn1 = *(const s16x8*)&qrow_p[(h+1)*64 + 32 + kgrp*8];
    }
    if (h + 2 < 16) stage(h+2, (h+2) & 3);
    __builtin_amdgcn_sched_barrier(0);
    if (h < 14)      asm volatile("s_waitcnt vmcnt(8)" ::: "memory");
    else if (h < 15) asm volatile("s_waitcnt vmcnt(6)" ::: "memory");
    else             asm volatile("s_waitcnt vmcnt(2)" ::: "memory");
    __builtin_amdgcn_sched_barrier(0);
    __builtin_amdgcn_s_barrier();
    __builtin_amdgcn_sched_barrier(0);

    const unsigned short* kl = &Kst[h & 3][0];
    #pragma unroll
    for (int ks = 0; ks < 4; ks++){
      s16x8 a0 = *(const s16x8*)&kl[e0[ks]];
      s16x8 a1 = *(const s16x8*)&kl[e0[ks] ^ 32];
      f32x4 sc = __builtin_amdgcn_mfma_f32_16x16x32_bf16(a0, qf0, (f32x4){0.f,0.f,0.f,0.f}, 0, 0, 0);
      sc = __builtin_amdgcn_mfma_f32_16x16x32_bf16(a1, qf1, sc, 0, 0, 0);
      #pragma unroll
      for (int j = 0; j < 4; j++) esum[ks][j] += __expf(sc[j]);
    }
    if (h < 15){ qf0 = qn0; qf1 = qn1; }
  }

  int qcol = qt*64 + w*16 + row_l;
  float* dst = invDQ + (size_t)b*4194304 + (size_t)qcol*2048 + kt*64 + kgrp*4;
  #pragma unroll
  for (int ks = 0; ks < 4; ks++){
    f32x4 rv;
    #pragma unroll
    for (int j = 0; j < 4; j++) rv[j] = 1.f / esum[ks][j];
    *(f32x4*)&dst[ks*16] = rv;
  }
}

// ---------------- PV-pass v3: barrier-free single-wave blocks, reg-direct K/V/invD ----------------
// grid 4096 = (b, h, pair i, half, w); 64 threads. All fragments global->VGPR, single-buffer
// register rotation (reload kt+1 into same regs after last use of kt). Per-wave private Ws in LDS
// for the score->A-fragment transpose. No barriers, no manual waitcnt.
__launch_bounds__(64, 4)
__global__ void pv_kernel(const unsigned short* __restrict__ qbuf,
                          const unsigned short* __restrict__ kb,
                          const unsigned short* __restrict__ vt,
                          const float* __restrict__ invDQ,
                          const float* __restrict__ sufv,
                          unsigned short* __restrict__ ab,
                          float* __restrict__ pb)
{
  __shared__ unsigned short Wsw[16 * 72];

  int bid = blockIdx.x;                              // 4096 = 8 * 512
  int blk = ((bid & 7) << 9) | (bid >> 3);           // XCD swizzle (bijective)
  int w    = blk & 3;
  int half = (blk >> 2) & 1;
  int i    = (blk >> 3) & 15;
  int h    = (blk >> 7) & 15;
  int b    = blk >> 11;
  int qsm = i, qbig = 31 - i;

  int lane = threadIdx.x & 63;
  int row_l = lane & 15, kgrp = lane >> 4;

  const unsigned short* KT = kb + (size_t)((b*16 + h)*32) * 4096;
  const unsigned short* VT = vt + (size_t)((b*16 + h)*32) * 4096;

  int eK[4];
  #pragma unroll
  for (int ks = 0; ks < 4; ks++)
    eK[ks] = ((ks*16 + row_l)*64 + kgrp*8) ^ ((row_l & 7) << 3);

  auto run = [&](int qt, int k0t, int k1t, int mode){
    int q0 = qt * 64;
    int qv = q0 + w*16 + row_l;
    const unsigned short* qrow_p = qbuf + (size_t)(b*2048 + qv) * 1024 + h*64;
    s16x8 qf0 = *(const s16x8*)&qrow_p[kgrp*8];
    s16x8 qf1 = *(const s16x8*)&qrow_p[32 + kgrp*8];
    const float* ivrow = invDQ + (size_t)b*4194304 + (size_t)qv*2048 + kgrp*4;

    f32x4 pvv[4];
    #pragma unroll
    for (int d = 0; d < 4; d++) pvv[d] = (f32x4){0.f,0.f,0.f,0.f};

    // prologue: load tile k0t fragments into registers
    const unsigned short* kp = KT + (size_t)k0t*4096;
    const unsigned short* vp = VT + (size_t)k0t*4096;
    s16x8 kr[8], vr[8];
    #pragma unroll
    for (int ks = 0; ks < 4; ks++){
      kr[2*ks]   = *(const s16x8*)&kp[eK[ks]];
      kr[2*ks+1] = *(const s16x8*)&kp[eK[ks] ^ 32];
    }
    #pragma unroll
    for (int kc = 0; kc < 2; kc++)
      #pragma unroll
      for (int dq = 0; dq < 4; dq++)
        vr[kc*4+dq] = *(const s16x8*)&vp[eK[dq] ^ (kc*32)];

    for (int kt = k0t; kt < k1t; kt++){
      bool nx = (kt + 1 < k1t);
      const unsigned short* kn = KT + (size_t)(kt+1)*4096;
      const unsigned short* vn = VT + (size_t)(kt+1)*4096;
      // invD for this tile (lead ~QK-phase before use)
      f32x4 iv[4];
      #pragma unroll
      for (int ks = 0; ks < 4; ks++)
        iv[ks] = *(const f32x4*)&ivrow[kt*64 + ks*16];

      int kbase = kt*64 + kgrp*4;
      #pragma unroll
      for (int ks = 0; ks < 4; ks++){
        f32x4 sc = __builtin_amdgcn_mfma_f32_16x16x32_bf16(kr[2*ks], qf0, (f32x4){0.f,0.f,0.f,0.f}, 0, 0, 0);
        sc = __builtin_amdgcn_mfma_f32_16x16x32_bf16(kr[2*ks+1], qf1, sc, 0, 0, 0);
        if (nx){                      // reload K regs for kt+1 (WAR after use)
          kr[2*ks]   = *(const s16x8*)&kn[eK[ks]];
          kr[2*ks+1] = *(const s16x8*)&kn[eK[ks] ^ 32];
        }
        #pragma unroll
        for (int j = 0; j < 4; j++){
          float e = __expf(sc[j]);
          sc[j] = (kbase + ks*16 + j > qv) ? 0.0625f : e * iv[ks][j];
        }
        unsigned lo, hi;
        asm("v_cvt_pk_bf16_f32 %0, %1, %2" : "=v"(lo) : "v"(sc[0]), "v"(sc[1]));
        asm("v_cvt_pk_bf16_f32 %0, %1, %2" : "=v"(hi) : "v"(sc[2]), "v"(sc[3]));
        uint2 pk2; pk2.x = lo; pk2.y = hi;
        *(uint2*)&Wsw[row_l*72 + ks*16 + kgrp*4] = pk2;
      }
      // PV (per-wave private Ws: lgkm dependency only, no barrier)
      #pragma unroll
      for (int kc = 0; kc < 2; kc++){
        s16x8 af = *(const s16x8*)&Wsw[row_l*72 + kc*32 + kgrp*8];
        #pragma unroll
        for (int dq = 0; dq < 4; dq++)
          pvv[dq] = __builtin_amdgcn_mfma_f32_16x16x32_bf16(af, vr[kc*4+dq], pvv[dq], 0, 0, 0);
      }
      if (nx){                        // reload V regs for kt+1
        #pragma unroll
        for (int kc = 0; kc < 2; kc++)
          #pragma unroll
          for (int dq = 0; dq < 4; dq++)
            vr[kc*4+dq] = *(const s16x8*)&vn[eK[dq] ^ (kc*32)];
      }
    }

    // epilogue: out rows q = q0 + w*16 + kgrp*4 + j; cols d = dq*16 + row_l
    if (mode == 0){
      int tsuf = qt + 1;
      #pragma unroll
      for (int dq = 0; dq < 4; dq++){
        int d = dq*16 + row_l;
        float suf = sufv[((size_t)(b*16 + h)*33 + tsuf)*64 + d];
        #pragma unroll
        for (int j = 0; j < 4; j++){
          int qo = q0 + w*16 + kgrp*4 + j;
          ab[(size_t)(b*2048 + qo)*1024 + h*64 + d] = f2bf(pvv[dq][j] + 0.0625f * suf);
        }
      }
    } else {
      float* pr = pb + ((size_t)((b*16 + h)*16 + i)*2 + (mode - 1)) * 4096;
      #pragma unroll
      for (int dq = 0; dq < 4; dq++){
        int d = dq*16 + row_l;
        #pragma unroll
        for (int j = 0; j < 4; j++)
          pr[(w*16 + kgrp*4 + j)*64 + d] = pvv[dq][j];
      }
    }
  };

  if (half == 0){
    run(qsm, 0, i + 1, 0);
    run(qbig, 0, 16 - i, 1);
  } else {
    run(qbig, 16 - i, 32 - i, 2);
  }
}

// ---------------- reduce split partials + suffix tail -> abuf ----------------
__global__ void reduce_kernel(const float* __restrict__ pb,
                              const float* __restrict__ sufv,
                              unsigned short* __restrict__ ab)
{
  int blk = blockIdx.x;               // 512 = (b,h,i)
  int b = blk >> 8, rr = blk & 255;
  int h = rr >> 4, i = rr & 15;
  int qbig = 31 - i, tsuf = 32 - i;
  int t = threadIdx.x;
  int q = t >> 2, dbase = (t & 3) * 16;
  const float* p0 = pb + ((size_t)((b*16 + h)*16 + i)*2 + 0)*4096 + q*64 + dbase;
  const float* p1 = p0 + 4096;
  const float* sf = sufv + ((size_t)(b*16 + h)*33 + tsuf)*64 + dbase;
  unsigned short* op = ab + (size_t)(b*2048 + qbig*64 + q)*1024 + h*64 + dbase;
  #pragma unroll
  for (int e = 0; e < 4; e++){
    float4 a = *(const float4*)(p0 + e*4);
    float4 bb = *(const float4*)(p1 + e*4);
    float4 s = *(const float4*)(sf + e*4);
    unsigned short o[4];
    o[0] = f2bf(a.x + bb.x + 0.0625f * s.x);
    o[1] = f2bf(a.y + bb.y + 0.0625f * s.y);
    o[2] = f2bf(a.z + bb.z + 0.0625f * s.z);
    o[3] = f2bf(a.w + bb.w + 0.0625f * s.w);
    *(s16x4*)(op + e*4) = *(s16x4*)o;
  }
}

// ---------------- host ----------------
extern "C" void kernel_launch(void* const* d_in, const int* in_sizes, int n_in,
                              void* d_out, int out_size, void* d_ws, size_t ws_size,
                              hipStream_t stream) {
  (void)in_sizes; (void)n_in; (void)out_size; (void)ws_size;
  const float* x  = (const float*)d_in[0];
  const float* Wa = (const float*)d_in[1];
  const float* ba = (const float*)d_in[2];
  const float* Wp = (const float*)d_in[3];
  const float* bp = (const float*)d_in[4];
  float* out = (float*)d_out;

  char* ws = (char*)d_ws;
  size_t off = 0;
  auto alloc = [&](size_t bytes) -> void* {
    void* p = ws + off;
    off += (bytes + 255) & ~(size_t)255;
    return p;
  };
  // region A (16 MB): xb (8 MB) + WaT (6 MB) alias pbuf — both dead before pv_kernel writes partials
  float* pbuf          = (float*)alloc((size_t)16*1024*1024);
  unsigned short* xb   = (unsigned short*)((char*)pbuf);
  unsigned short* WaT  = (unsigned short*)((char*)pbuf + (size_t)4096*1024*2);
  unsigned short* WpT  = (unsigned short*)alloc((size_t)1024*1024*2);
  unsigned short* qbuf = (unsigned short*)alloc((size_t)4096*1024*2);
  unsigned short* ktile= (unsigned short*)alloc((size_t)4096*1024*2);
  unsigned short* vtile= (unsigned short*)alloc((size_t)4096*1024*2);
  unsigned short* abuf = (unsigned short*)alloc((size_t)4096*1024*2);
  float* invDQ         = (float*)alloc((size_t)2*2048*2048*4);
  float* sufv          = (float*)alloc((size_t)32*33*64*4);

  // 1) conversions
  cvt_kernel<<<2048, 256, 0, stream>>>(x, xb, 4096*1024/8);
  transpose_cvt<<<dim3(3072/32, 1024/32), dim3(32, 8), 0, stream>>>(Wa, WaT, 1024, 3072);
  transpose_cvt<<<dim3(1024/32, 1024/32), dim3(32, 8), 0, stream>>>(Wp, WpT, 1024, 1024);

  // 2) QKV GEMM -> qbuf / ktile / vtile
  gemm_kernel<0,128><<<dim3(24, 32), 256, 0, stream>>>(xb, WaT, ba, 3072, qbuf, ktile, vtile, nullptr);

  // 3) V suffix sums
  sufv_kernel<<<32, 256, 0, stream>>>(vtile, sufv);

  // 4) denominator pass
  dpass_kernel<<<1056, 256, 0, stream>>>(qbuf, ktile, invDQ);

  // 5) PV pass (barrier-free, single-wave blocks)
  pv_kernel<<<4096, 64, 0, stream>>>(qbuf, ktile, vtile, invDQ, sufv, abuf, pbuf);

  // 6) reduce split partials
  reduce_kernel<<<512, 256, 0, stream>>>(pbuf, sufv, abuf);

  // 7) projection GEMM (BM=64 -> 512 blocks, 2/CU)
  gemm_kernel<1,64><<<dim3(1024/128, 4096/64), 256, 0, stream>>>(abuf, WpT, bp, 1024, nullptr, nullptr, nullptr, out);
}

// Round 7
// 178.698 us; speedup vs baseline: 1.5319x; 1.5319x over previous
//
#include <hip/hip_runtime.h>

#define DI __device__ __forceinline__

typedef __attribute__((ext_vector_type(8))) short s16x8;
typedef __attribute__((ext_vector_type(4))) short s16x4;
typedef __attribute__((ext_vector_type(4))) float f32x4;

DI unsigned short f2bf(float f){
  unsigned u = __float_as_uint(f);
  u = (u + 0x7FFFu + ((u >> 16) & 1u)) >> 16;
  return (unsigned short)u;
}
DI float bf2f(unsigned short h){
  return __uint_as_float(((unsigned)h) << 16);
}
DI float exp2i(float x){ float r; asm("v_exp_f32 %0, %1" : "=v"(r) : "v"(x)); return r; }

DI void gll16(const void* g, void* l){
  __builtin_amdgcn_global_load_lds((const __attribute__((address_space(1))) void*)g,
                                   (__attribute__((address_space(3))) void*)l, 16, 0, 0);
}

#define VMCNT(n) asm volatile("s_waitcnt vmcnt(" #n ")" ::: "memory")

// ---------------- elementwise fp32 -> bf16 ----------------
__global__ void cvt_kernel(const float* __restrict__ in, unsigned short* __restrict__ out, int n8){
  int i = blockIdx.x * blockDim.x + threadIdx.x;
  if (i >= n8) return;
  const float4* p = (const float4*)in + (size_t)i * 2;
  float4 a = p[0], b = p[1];
  s16x8 o;
  o[0] = (short)f2bf(a.x); o[1] = (short)f2bf(a.y); o[2] = (short)f2bf(a.z); o[3] = (short)f2bf(a.w);
  o[4] = (short)f2bf(b.x); o[5] = (short)f2bf(b.y); o[6] = (short)f2bf(b.z); o[7] = (short)f2bf(b.w);
  ((s16x8*)out)[i] = o;
}

// ---------------- transpose + convert: in fp32 [R][C] -> out bf16 [C][R] ----------------
__global__ void transpose_cvt(const float* __restrict__ in, unsigned short* __restrict__ out, int R, int C){
  __shared__ float t[32][33];
  int c0 = blockIdx.x * 32, r0 = blockIdx.y * 32;
  int tx = threadIdx.x, ty = threadIdx.y; // 32 x 8
  #pragma unroll
  for (int i = 0; i < 4; i++)
    t[ty + i*8][tx] = in[(size_t)(r0 + ty + i*8) * C + c0 + tx];
  __syncthreads();
  #pragma unroll
  for (int i = 0; i < 4; i++)
    out[(size_t)(c0 + ty + i*8) * R + r0 + tx] = f2bf(t[tx][ty + i*8]);
}

// ---------------- GEMM (m97 structure): C[M x N] = A[M x K] * Wt[N x K]^T + bias ----------------
// MODE 0 (BM=128): qkv -> qbuf rows (Q pre-scaled by log2e), ktile swz, vtile swz.
// MODE 1 (BM=64): proj -> fp32 out.
template<int MODE, int BM>
__launch_bounds__(256)
__global__ void gemm_kernel(const unsigned short* __restrict__ A,
                            const unsigned short* __restrict__ Wt,
                            const float* __restrict__ bias,
                            int N,
                            unsigned short* __restrict__ qb,
                            unsigned short* __restrict__ kb,
                            unsigned short* __restrict__ vt,
                            float* __restrict__ out)
{
  constexpr int MI = BM / 32;
  constexpr int AC = BM / 32;
  const int K = 1024;
  __shared__ unsigned short As[BM * 64];
  __shared__ unsigned short Bs[128 * 64];
  int m0 = blockIdx.y * BM, n0 = blockIdx.x * 128;
  int tid = threadIdx.x;
  int lane = tid & 63, w = tid >> 6;
  int row_l = lane & 15, kgrp = lane >> 4;
  int wm = (w >> 1) * (MI * 16), wn = (w & 1) * 64;

  const unsigned short* asrc[AC];
  const unsigned short* bsrc[4];
  int ldsoA[AC], ldsoB[4];
  int chunk = (lane & 7) ^ (lane >> 3);
  #pragma unroll
  for (int c4 = 0; c4 < AC; c4++){
    int r = c4*32 + w*8 + (lane >> 3);
    asrc[c4] = A + (size_t)(m0 + r) * K + chunk*8;
    ldsoA[c4] = (c4*32 + w*8) * 64;
  }
  #pragma unroll
  for (int c4 = 0; c4 < 4; c4++){
    int r = c4*32 + w*8 + (lane >> 3);
    bsrc[c4] = Wt + (size_t)(n0 + r) * K + chunk*8;
    ldsoB[c4] = (c4*32 + w*8) * 64;
  }
  int eA[MI], eB[4];
  #pragma unroll
  for (int i = 0; i < MI; i++){
    int ra = wm + i*16 + row_l;
    eA[i] = (ra*64 + kgrp*8) ^ ((ra & 7) << 3);
  }
  #pragma unroll
  for (int i = 0; i < 4; i++){
    int rb = wn + i*16 + row_l;
    eB[i] = (rb*64 + kgrp*8) ^ ((rb & 7) << 3);
  }

  f32x4 acc[MI][4];
  #pragma unroll
  for (int i = 0; i < MI; i++)
    #pragma unroll
    for (int j = 0; j < 4; j++)
      acc[i][j] = (f32x4){0.f, 0.f, 0.f, 0.f};

  for (int k0 = 0; k0 < K; k0 += 64){
    #pragma unroll
    for (int c4 = 0; c4 < AC; c4++)
      gll16(asrc[c4] + k0, (void*)(As + ldsoA[c4]));
    #pragma unroll
    for (int c4 = 0; c4 < 4; c4++)
      gll16(bsrc[c4] + k0, (void*)(Bs + ldsoB[c4]));
    __syncthreads();
    #pragma unroll
    for (int kc = 0; kc < 2; kc++){
      s16x8 af[MI], bfr[4];
      #pragma unroll
      for (int mi = 0; mi < MI; mi++)
        af[mi] = *(const s16x8*)&As[eA[mi] ^ (kc*32)];
      #pragma unroll
      for (int ni = 0; ni < 4; ni++)
        bfr[ni] = *(const s16x8*)&Bs[eB[ni] ^ (kc*32)];
      #pragma unroll
      for (int mi = 0; mi < MI; mi++)
        #pragma unroll
        for (int ni = 0; ni < 4; ni++)
          acc[mi][ni] = __builtin_amdgcn_mfma_f32_16x16x32_bf16(af[mi], bfr[ni], acc[mi][ni], 0, 0, 0);
    }
    __syncthreads();
  }

  #pragma unroll
  for (int mi = 0; mi < MI; mi++){
    #pragma unroll
    for (int ni = 0; ni < 4; ni++){
      #pragma unroll
      for (int j = 0; j < 4; j++){
        int gr = m0 + wm + mi*16 + kgrp*4 + j;
        int gc = n0 + wn + ni*16 + row_l;
        float v = acc[mi][ni][j] + bias[gc];
        if (MODE == 0){
          int h = gc / 192, cc = gc % 192;
          int b = gr >> 11, s = gr & 2047;
          if (cc < 64){
            // Q pre-scaled by log2(e): downstream uses raw v_exp_f32 (exp2)
            qb[(size_t)gr * 1024 + h*64 + cc] = f2bf(v * 1.44269504f);
          } else if (cc < 128){
            int d = cc - 64; int kt = s >> 6, kk = s & 63;
            kb[(size_t)((b*16 + h)*32 + kt) * 4096 + ((kk*64 + d) ^ ((kk & 7) << 3))] = f2bf(v);
          } else {
            int d = cc - 128; int kt = s >> 6, kk = s & 63;
            vt[(size_t)((b*16 + h)*32 + kt) * 4096 + ((d*64 + kk) ^ ((d & 7) << 3))] = f2bf(v);
          }
        } else {
          out[(size_t)gr * N + gc] = v;
        }
      }
    }
  }
}

// ---------------- V suffix sums (64-key granularity): sufv[bh][t in 0..32][64d] ----------------
__global__ void sufv_kernel(const unsigned short* __restrict__ vt, float* __restrict__ sufv){
  __shared__ float tot[4][64];
  int bh = blockIdx.x;                 // 32
  int tid = threadIdx.x;               // 256
  int tq = tid >> 6, d = tid & 63;
  const unsigned short* base = vt + (size_t)bh * 32 * 4096;
  float s[8];
  float run = 0.f;
  for (int j = 7; j >= 0; j--){
    int t = tq*8 + j;
    float rs = 0.f;
    #pragma unroll
    for (int c = 0; c < 8; c++){
      int idx = (d*64 + c*8) ^ ((d & 7) << 3);
      s16x8 v = *(const s16x8*)&base[(size_t)t*4096 + idx];
      #pragma unroll
      for (int e = 0; e < 8; e++) rs += bf2f((unsigned short)v[e]);
    }
    run += rs; s[j] = run;
  }
  tot[tq][d] = run;
  __syncthreads();
  float carry = 0.f;
  for (int t2 = tq+1; t2 < 4; t2++) carry += tot[t2][d];
  #pragma unroll
  for (int j = 0; j < 8; j++)
    sufv[((size_t)bh*33 + tq*8 + j)*64 + d] = s[j] + carry;
  if (tid < 64) sufv[((size_t)bh*33 + 32)*64 + tid] = 0.f;
}

// ---------------- D-pass: invb[b][q][k] (bf16) = 1 / sum_h exp(s_h(q,k)) over causal triangle ----------------
// kt-major tile enumeration + XCD swizzle; 4-buffer 2-deep LDS ring. Q pre-scaled -> raw exp2.
__launch_bounds__(256)
__global__ void dpass_kernel(const unsigned short* __restrict__ qbuf,
                             const unsigned short* __restrict__ kb,
                             unsigned short* __restrict__ invb)
{
  __shared__ unsigned short Kst[4][4096];
  int bid = blockIdx.x;                       // 1056 = 8 * 132
  int blk = (bid & 7) * 132 + (bid >> 3);     // XCD swizzle (bijective)
  int b = blk / 528, t = blk % 528;
  int kt = (int)(32.5f - sqrtf(1056.25f - 2.f*t));
  while (kt*(65-kt)/2 > t) kt--;
  while ((kt+1)*(64-kt)/2 <= t) kt++;
  int qt = kt + (t - kt*(65-kt)/2);

  int tid = threadIdx.x, lane = tid & 63, w = tid >> 6;
  int row_l = lane & 15, kgrp = lane >> 4;

  const unsigned short* ktb = kb + ((size_t)(b*16)*32 + kt) * 4096;
  int sgoff = (w*128 + lane)*8;

  auto stage = [&](int hh, int buf){
    const unsigned short* src = ktb + (size_t)hh * 131072;
    gll16(src + sgoff,       (void*)(&Kst[buf][0] + w*1024));
    gll16(src + sgoff + 512, (void*)(&Kst[buf][0] + w*1024 + 512));
  };

  int e0[4];
  #pragma unroll
  for (int ks = 0; ks < 4; ks++){
    int row = ks*16 + row_l;
    e0[ks] = (row*64 + kgrp*8) ^ ((row & 7) << 3);
  }

  stage(0, 0);
  stage(1, 1);

  f32x4 esum[4];
  #pragma unroll
  for (int ks = 0; ks < 4; ks++) esum[ks] = (f32x4){0.f,0.f,0.f,0.f};

  const unsigned short* qrow_p = qbuf + (size_t)(b*2048 + qt*64 + w*16 + row_l) * 1024;
  s16x8 qf0 = *(const s16x8*)&qrow_p[kgrp*8];
  s16x8 qf1 = *(const s16x8*)&qrow_p[32 + kgrp*8];

  for (int h = 0; h < 16; h++){
    s16x8 qn0, qn1;
    if (h < 15){
      qn0 = *(const s16x8*)&qrow_p[(h+1)*64 + kgrp*8];
      qn1 = *(const s16x8*)&qrow_p[(h+1)*64 + 32 + kgrp*8];
    }
    if (h + 2 < 16) stage(h+2, (h+2) & 3);
    __builtin_amdgcn_sched_barrier(0);
    if (h < 14)      VMCNT(8);
    else if (h < 15) VMCNT(6);
    else             VMCNT(2);
    __builtin_amdgcn_sched_barrier(0);
    __builtin_amdgcn_s_barrier();
    __builtin_amdgcn_sched_barrier(0);

    const unsigned short* kl = &Kst[h & 3][0];
    #pragma unroll
    for (int ks = 0; ks < 4; ks++){
      s16x8 a0 = *(const s16x8*)&kl[e0[ks]];
      s16x8 a1 = *(const s16x8*)&kl[e0[ks] ^ 32];
      f32x4 sc = __builtin_amdgcn_mfma_f32_16x16x32_bf16(a0, qf0, (f32x4){0.f,0.f,0.f,0.f}, 0, 0, 0);
      sc = __builtin_amdgcn_mfma_f32_16x16x32_bf16(a1, qf1, sc, 0, 0, 0);
      #pragma unroll
      for (int j = 0; j < 4; j++) esum[ks][j] += exp2i(sc[j]);
    }
    if (h < 15){ qf0 = qn0; qf1 = qn1; }
  }

  int qcol = qt*64 + w*16 + row_l;
  unsigned short* dst = invb + (size_t)b*4194304 + (size_t)qcol*2048 + kt*64 + kgrp*4;
  #pragma unroll
  for (int ks = 0; ks < 4; ks++){
    float r0 = 1.f/esum[ks][0], r1 = 1.f/esum[ks][1];
    float r2 = 1.f/esum[ks][2], r3 = 1.f/esum[ks][3];
    unsigned lo, hi;
    asm("v_cvt_pk_bf16_f32 %0, %1, %2" : "=v"(lo) : "v"(r0), "v"(r1));
    asm("v_cvt_pk_bf16_f32 %0, %1, %2" : "=v"(hi) : "v"(r2), "v"(r3));
    uint2 pk; pk.x = lo; pk.y = hi;
    *(uint2*)&dst[ks*16] = pk;
  }
}

// ---------------- PV-pass: 4-wave shared staging, K ring 3 (lead 2), V ring 2 (lead 1),
// invD bf16 depth-2 register prefetch, diag-only masking, setprio MFMA clusters.
// grid 1024 = (b, h, pair i, half) XCD-swizzled; 49KB LDS -> 3 blocks/CU.
__launch_bounds__(256, 3)
__global__ void pv_kernel(const unsigned short* __restrict__ qbuf,
                          const unsigned short* __restrict__ kb,
                          const unsigned short* __restrict__ vt,
                          const unsigned short* __restrict__ invb,
                          const float* __restrict__ sufv,
                          unsigned short* __restrict__ ab,
                          float* __restrict__ pb)
{
  __shared__ unsigned short Kst[3][4096];
  __shared__ unsigned short Vst[2][4096];
  __shared__ unsigned short Wsh[4][1152];

  int blk = ((blockIdx.x & 7) << 7) + (blockIdx.x >> 3);   // XCD swizzle, 1024 = 8*128
  int b = blk >> 9;
  int r = blk & 511;
  int h = r >> 5;
  int r2 = r & 31;
  int i = r2 >> 1, half = r2 & 1;
  int qsm = i, qbig = 31 - i;

  int tid = threadIdx.x, lane = tid & 63, w = tid >> 6;
  int row_l = lane & 15, kgrp = lane >> 4;

  const unsigned short* KT = kb + (size_t)((b*16 + h)*32) * 4096;
  const unsigned short* VT = vt + (size_t)((b*16 + h)*32) * 4096;
  int sgoff = (w*128 + lane)*8;
  unsigned short* Wsw = &Wsh[w][0];

  int eK[4];
  #pragma unroll
  for (int ks = 0; ks < 4; ks++){
    int row = ks*16 + row_l;
    eK[ks] = (row*64 + kgrp*8) ^ ((row & 7) << 3);
  }

  auto stageK = [&](int kt, int buf){
    gll16(KT + (size_t)kt*4096 + sgoff,       (void*)(&Kst[buf][0] + w*1024));
    gll16(KT + (size_t)kt*4096 + sgoff + 512, (void*)(&Kst[buf][0] + w*1024 + 512));
  };
  auto stageV = [&](int kt, int buf){
    gll16(VT + (size_t)kt*4096 + sgoff,       (void*)(&Vst[buf][0] + w*1024));
    gll16(VT + (size_t)kt*4096 + sgoff + 512, (void*)(&Vst[buf][0] + w*1024 + 512));
  };

  auto run = [&](int qt, int k0t, int k1t, int mode){
    int q0 = qt * 64;
    int qv = q0 + w*16 + row_l;
    const unsigned short* qrow_p = qbuf + (size_t)(b*2048 + qv) * 1024 + h*64;
    s16x8 qf0 = *(const s16x8*)&qrow_p[kgrp*8];
    s16x8 qf1 = *(const s16x8*)&qrow_p[32 + kgrp*8];
    const unsigned short* ivrow = invb + (size_t)b*4194304 + (size_t)qv*2048 + kgrp*4;

    f32x4 pvv[4];
    #pragma unroll
    for (int d = 0; d < 4; d++) pvv[d] = (f32x4){0.f,0.f,0.f,0.f};

    __syncthreads();                         // buffers free (prev segment fully done)
    // prologue: K(k0) -> i1 -> V(k0) -> [K(k0+1), i2]
    stageK(k0t, 0);
    s16x4 i1[4], i2[4];
    #pragma unroll
    for (int ks = 0; ks < 4; ks++) i1[ks] = *(const s16x4*)&ivrow[k0t*64 + ks*16];
    stageV(k0t, 0);
    if (k0t + 1 < k1t){
      stageK(k0t+1, 1);
      #pragma unroll
      for (int ks = 0; ks < 4; ks++) i2[ks] = *(const s16x4*)&ivrow[(k0t+1)*64 + ks*16];
    }

    for (int kt = k0t; kt < k1t; kt++){
      int bK = (kt - k0t) % 3, bV = (kt - k0t) & 1;
      bool nx1 = (kt + 1 < k1t), nx2 = (kt + 2 < k1t);

      __builtin_amdgcn_s_barrier();          // A: all waves done reading bufs being restaged
      if (nx2) stageK(kt+2, (kt+2-k0t) % 3);
      if (nx1) stageV(kt+1, bV ^ 1);
      __builtin_amdgcn_sched_barrier(0);
      // newer-than-stageV(kt) op count (FIFO audit incl. prologue peel)
      int N = (kt == k0t) ? (nx1 ? (nx2 ? 10 : 8) : 0)
                          : (nx2 ? 8 : (nx1 ? 6 : 0));
      if (N == 10)     VMCNT(10);
      else if (N == 8) VMCNT(8);
      else if (N == 6) VMCNT(6);
      else             VMCNT(0);
      __builtin_amdgcn_sched_barrier(0);
      __builtin_amdgcn_s_barrier();          // B: publish tile kt
      __builtin_amdgcn_sched_barrier(0);

      s16x4 icur[4];
      #pragma unroll
      for (int ks = 0; ks < 4; ks++){ icur[ks] = i1[ks]; i1[ks] = i2[ks]; }
      if (nx2){
        #pragma unroll
        for (int ks = 0; ks < 4; ks++) i2[ks] = *(const s16x4*)&ivrow[(kt+2)*64 + ks*16];
      }

      const unsigned short* kl = &Kst[bK][0];
      const unsigned short* vl = &Vst[bV][0];
      // QK^T (swapped: rows=key, cols=q); Q pre-scaled by log2e
      f32x4 sc[4];
      __builtin_amdgcn_s_setprio(1);
      #pragma unroll
      for (int ks = 0; ks < 4; ks++){
        s16x8 a0 = *(const s16x8*)&kl[eK[ks]];
        s16x8 a1 = *(const s16x8*)&kl[eK[ks] ^ 32];
        sc[ks] = __builtin_amdgcn_mfma_f32_16x16x32_bf16(a0, qf0, (f32x4){0.f,0.f,0.f,0.f}, 0, 0, 0);
        sc[ks] = __builtin_amdgcn_mfma_f32_16x16x32_bf16(a1, qf1, sc[ks], 0, 0, 0);
      }
      __builtin_amdgcn_s_setprio(0);

      // weights: w = exp2(s') * invD  (masked -> exactly 1/16, only on diagonal tile)
      if (kt == qt){
        int kbase = kt*64 + kgrp*4;
        #pragma unroll
        for (int ks = 0; ks < 4; ks++){
          #pragma unroll
          for (int j = 0; j < 4; j++){
            float wv = exp2i(sc[ks][j]) * bf2f((unsigned short)icur[ks][j]);
            sc[ks][j] = (kbase + ks*16 + j > qv) ? 0.0625f : wv;
          }
          unsigned lo, hi;
          asm("v_cvt_pk_bf16_f32 %0, %1, %2" : "=v"(lo) : "v"(sc[ks][0]), "v"(sc[ks][1]));
          asm("v_cvt_pk_bf16_f32 %0, %1, %2" : "=v"(hi) : "v"(sc[ks][2]), "v"(sc[ks][3]));
          uint2 pk2; pk2.x = lo; pk2.y = hi;
          *(uint2*)&Wsw[row_l*72 + ks*16 + kgrp*4] = pk2;
        }
      } else {
        #pragma unroll
        for (int ks = 0; ks < 4; ks++){
          #pragma unroll
          for (int j = 0; j < 4; j++)
            sc[ks][j] = exp2i(sc[ks][j]) * bf2f((unsigned short)icur[ks][j]);
          unsigned lo, hi;
          asm("v_cvt_pk_bf16_f32 %0, %1, %2" : "=v"(lo) : "v"(sc[ks][0]), "v"(sc[ks][1]));
          asm("v_cvt_pk_bf16_f32 %0, %1, %2" : "=v"(hi) : "v"(sc[ks][2]), "v"(sc[ks][3]));
          uint2 pk2; pk2.x = lo; pk2.y = hi;
          *(uint2*)&Wsw[row_l*72 + ks*16 + kgrp*4] = pk2;
        }
      }

      // PV (per-wave private Ws: same-wave lgkm ordering, no barrier)
      __builtin_amdgcn_s_setprio(1);
      #pragma unroll
      for (int kc = 0; kc < 2; kc++){
        s16x8 af = *(const s16x8*)&Wsw[row_l*72 + kc*32 + kgrp*8];
        #pragma unroll
        for (int dq = 0; dq < 4; dq++){
          s16x8 vf = *(const s16x8*)&vl[eK[dq] ^ (kc*32)];
          pvv[dq] = __builtin_amdgcn_mfma_f32_16x16x32_bf16(af, vf, pvv[dq], 0, 0, 0);
        }
      }
      __builtin_amdgcn_s_setprio(0);
    }

    // epilogue: out rows q = q0 + w*16 + kgrp*4 + j; cols d = dq*16 + row_l
    if (mode == 0){
      int tsuf = qt + 1;
      #pragma unroll
      for (int dq = 0; dq < 4; dq++){
        int d = dq*16 + row_l;
        float suf = sufv[((size_t)(b*16 + h)*33 + tsuf)*64 + d];
        #pragma unroll
        for (int j = 0; j < 4; j++){
          int qo = q0 + w*16 + kgrp*4 + j;
          ab[(size_t)(b*2048 + qo)*1024 + h*64 + d] = f2bf(pvv[dq][j] + 0.0625f * suf);
        }
      }
    } else {
      float* pr = pb + ((size_t)((b*16 + h)*16 + i)*2 + (mode - 1)) * 4096;
      #pragma unroll
      for (int dq = 0; dq < 4; dq++){
        int d = dq*16 + row_l;
        #pragma unroll
        for (int j = 0; j < 4; j++)
          pr[(w*16 + kgrp*4 + j)*64 + d] = pvv[dq][j];
      }
    }
  };

  if (half == 0){
    run(qsm, 0, i + 1, 0);
    run(qbig, 0, 16 - i, 1);
  } else {
    run(qbig, 16 - i, 32 - i, 2);
  }
}

// ---------------- reduce split partials + suffix tail -> abuf ----------------
__global__ void reduce_kernel(const float* __restrict__ pb,
                              const float* __restrict__ sufv,
                              unsigned short* __restrict__ ab)
{
  int blk = blockIdx.x;               // 512 = (b,h,i)
  int b = blk >> 8, rr = blk & 255;
  int h = rr >> 4, i = rr & 15;
  int qbig = 31 - i, tsuf = 32 - i;
  int t = threadIdx.x;
  int q = t >> 2, dbase = (t & 3) * 16;
  const float* p0 = pb + ((size_t)((b*16 + h)*16 + i)*2 + 0)*4096 + q*64 + dbase;
  const float* p1 = p0 + 4096;
  const float* sf = sufv + ((size_t)(b*16 + h)*33 + tsuf)*64 + dbase;
  unsigned short* op = ab + (size_t)(b*2048 + qbig*64 + q)*1024 + h*64 + dbase;
  #pragma unroll
  for (int e = 0; e < 4; e++){
    float4 a = *(const float4*)(p0 + e*4);
    float4 bb = *(const float4*)(p1 + e*4);
    float4 s = *(const float4*)(sf + e*4);
    unsigned short o[4];
    o[0] = f2bf(a.x + bb.x + 0.0625f * s.x);
    o[1] = f2bf(a.y + bb.y + 0.0625f * s.y);
    o[2] = f2bf(a.z + bb.z + 0.0625f * s.z);
    o[3] = f2bf(a.w + bb.w + 0.0625f * s.w);
    *(s16x4*)(op + e*4) = *(s16x4*)o;
  }
}

// ---------------- host ----------------
extern "C" void kernel_launch(void* const* d_in, const int* in_sizes, int n_in,
                              void* d_out, int out_size, void* d_ws, size_t ws_size,
                              hipStream_t stream) {
  (void)in_sizes; (void)n_in; (void)out_size; (void)ws_size;
  const float* x  = (const float*)d_in[0];
  const float* Wa = (const float*)d_in[1];
  const float* ba = (const float*)d_in[2];
  const float* Wp = (const float*)d_in[3];
  const float* bp = (const float*)d_in[4];
  float* out = (float*)d_out;

  char* ws = (char*)d_ws;
  size_t off = 0;
  auto alloc = [&](size_t bytes) -> void* {
    void* p = ws + off;
    off += (bytes + 255) & ~(size_t)255;
    return p;
  };
  // region A (16 MB): xb (8 MB) + WaT (6 MB) alias pbuf — both dead before pv_kernel writes partials
  float* pbuf          = (float*)alloc((size_t)16*1024*1024);
  unsigned short* xb   = (unsigned short*)((char*)pbuf);
  unsigned short* WaT  = (unsigned short*)((char*)pbuf + (size_t)4096*1024*2);
  unsigned short* WpT  = (unsigned short*)alloc((size_t)1024*1024*2);
  unsigned short* qbuf = (unsigned short*)alloc((size_t)4096*1024*2);
  unsigned short* ktile= (unsigned short*)alloc((size_t)4096*1024*2);
  unsigned short* vtile= (unsigned short*)alloc((size_t)4096*1024*2);
  unsigned short* abuf = (unsigned short*)alloc((size_t)4096*1024*2);
  unsigned short* invb = (unsigned short*)alloc((size_t)2*2048*2048*2); // bf16 invD
  float* sufv          = (float*)alloc((size_t)32*33*64*4);

  // 1) conversions
  cvt_kernel<<<2048, 256, 0, stream>>>(x, xb, 4096*1024/8);
  transpose_cvt<<<dim3(3072/32, 1024/32), dim3(32, 8), 0, stream>>>(Wa, WaT, 1024, 3072);
  transpose_cvt<<<dim3(1024/32, 1024/32), dim3(32, 8), 0, stream>>>(Wp, WpT, 1024, 1024);

  // 2) QKV GEMM -> qbuf / ktile / vtile
  gemm_kernel<0,128><<<dim3(24, 32), 256, 0, stream>>>(xb, WaT, ba, 3072, qbuf, ktile, vtile, nullptr);

  // 3) V suffix sums
  sufv_kernel<<<32, 256, 0, stream>>>(vtile, sufv);

  // 4) denominator pass (bf16 invD)
  dpass_kernel<<<1056, 256, 0, stream>>>(qbuf, ktile, invb);

  // 5) PV pass
  pv_kernel<<<1024, 256, 0, stream>>>(qbuf, ktile, vtile, invb, sufv, abuf, pbuf);

  // 6) reduce split partials
  reduce_kernel<<<512, 256, 0, stream>>>(pbuf, sufv, abuf);

  // 7) projection GEMM (BM=64 -> 512 blocks, 2/CU)
  gemm_kernel<1,64><<<dim3(1024/128, 4096/64), 256, 0, stream>>>(abuf, WpT, bp, 1024, nullptr, nullptr, nullptr, out);
}